// Round 4
// baseline (196.025 us; speedup 1.0000x reference)
//
#include <hip/hip_runtime.h>

// ConcordanceCC: B=256 rows, T=65536 cols.
// Per-row sufficient statistics in fp64: L, Σy m, Σp m, Σy²m, Σp²m, Σyp m.
// Kernel 1: 2048 blocks (8 chunks/row), each reduces an 8192-elem chunk.
// Kernel 2: 1 block, 256 threads (1 thread/row), finalize ccc + mean.

#define B_ROWS 256
#define T_COLS 65536
#define CHUNKS 8                      // chunks per row
#define CHUNK_ELEMS (T_COLS / CHUNKS) // 8192
#define THREADS 256
#define VEC_ITERS (CHUNK_ELEMS / (THREADS * 4)) // 8 float4 iters/thread

__global__ __launch_bounds__(THREADS) void ccc_partial_kernel(
    const float* __restrict__ ytrue,
    const float* __restrict__ ypred,
    const int*   __restrict__ mask,
    double*      __restrict__ ws)
{
    const int blk   = blockIdx.x;
    const int row   = blk / CHUNKS;
    const int chunk = blk % CHUNKS;
    const long base = (long)row * T_COLS + (long)chunk * CHUNK_ELEMS;

    const float4* __restrict__ yt4 = (const float4*)(ytrue + base);
    const float4* __restrict__ yp4 = (const float4*)(ypred + base);
    const int4*   __restrict__ mm4 = (const int4*)(mask + base);

    const int t = threadIdx.x;

    double st = 0.0, sp = 0.0, stt = 0.0, spp = 0.0, stp = 0.0;
    int L = 0;

#pragma unroll
    for (int i = 0; i < VEC_ITERS; ++i) {
        const int idx = t + i * THREADS;      // coalesced: lane-contiguous float4
        const float4 a = yt4[idx];
        const float4 b = yp4[idx];
        const int4   m = mm4[idx];

#define ACC(AX, BX, MX)                                                   \
        {                                                                 \
            const float fm = (float)(MX);    /* 0.0f or 1.0f */           \
            const float ym = AX * fm;        /* exact */                  \
            const float pm = BX * fm;                                     \
            const double yd = (double)ym, pd = (double)pm;                \
            L  += (MX);                                                   \
            st += yd;                                                     \
            sp += pd;                                                     \
            stt = fma(yd, yd, stt);                                       \
            spp = fma(pd, pd, spp);                                       \
            stp = fma(yd, pd, stp);                                       \
        }
        ACC(a.x, b.x, m.x)
        ACC(a.y, b.y, m.y)
        ACC(a.z, b.z, m.z)
        ACC(a.w, b.w, m.w)
#undef ACC
    }

    // wave (64-lane) shuffle reduction, then LDS across the 4 waves
    double vals[6] = { (double)L, st, sp, stt, spp, stp };
#pragma unroll
    for (int k = 0; k < 6; ++k) {
#pragma unroll
        for (int off = 32; off > 0; off >>= 1) {
            vals[k] += __shfl_down(vals[k], off, 64);
        }
    }

    __shared__ double red[THREADS / 64][6];
    const int wave = t >> 6;
    const int lane = t & 63;
    if (lane == 0) {
#pragma unroll
        for (int k = 0; k < 6; ++k) red[wave][k] = vals[k];
    }
    __syncthreads();

    if (t < 6) {
        double s = 0.0;
#pragma unroll
        for (int w = 0; w < THREADS / 64; ++w) s += red[w][t];
        ws[(long)blk * 6 + t] = s;
    }
}

__global__ __launch_bounds__(B_ROWS) void ccc_final_kernel(
    const double* __restrict__ ws,
    float*        __restrict__ out)
{
    const int r = threadIdx.x;  // one thread per row

    double L = 0.0, st = 0.0, sp = 0.0, stt = 0.0, spp = 0.0, stp = 0.0;
    const double* p = ws + (long)r * CHUNKS * 6;
#pragma unroll
    for (int c = 0; c < CHUNKS; ++c) {
        L   += p[c * 6 + 0];
        st  += p[c * 6 + 1];
        sp  += p[c * 6 + 2];
        stt += p[c * 6 + 3];
        spp += p[c * 6 + 4];
        stp += p[c * 6 + 5];
    }

    const double mean_t = st / L;
    const double mean_p = sp / L;
    const double denom  = L - 1.0;
    const double var_t  = (stt - st * st / L) / denom;
    const double var_p  = (spp - sp * sp / L) / denom;
    const double cov    = (stp - st * sp / L) / denom;
    // NB: reference uses (mean_t - mean_p) * 2, not squared — reproduced.
    double ccc = 2.0 * cov / (var_t + var_p + 2.0 * (mean_t - mean_p));

    // block reduction of ccc over 256 rows
#pragma unroll
    for (int off = 32; off > 0; off >>= 1) {
        ccc += __shfl_down(ccc, off, 64);
    }
    __shared__ double red[B_ROWS / 64];
    const int wave = r >> 6;
    const int lane = r & 63;
    if (lane == 0) red[wave] = ccc;
    __syncthreads();

    if (r == 0) {
        double s = 0.0;
#pragma unroll
        for (int w = 0; w < B_ROWS / 64; ++w) s += red[w];
        out[0] = (float)(s / (double)B_ROWS);
    }
}

extern "C" void kernel_launch(void* const* d_in, const int* in_sizes, int n_in,
                              void* d_out, int out_size, void* d_ws, size_t ws_size,
                              hipStream_t stream) {
    const float* ytrue = (const float*)d_in[0];
    const float* ypred = (const float*)d_in[1];
    const int*   mask  = (const int*)d_in[2];
    float* out = (float*)d_out;
    double* ws = (double*)d_ws;   // needs B_ROWS*CHUNKS*6*8 = 96 KiB

    ccc_partial_kernel<<<B_ROWS * CHUNKS, THREADS, 0, stream>>>(ytrue, ypred, mask, ws);
    ccc_final_kernel<<<1, B_ROWS, 0, stream>>>(ws, out);
}